// Round 1
// baseline (164.843 us; speedup 1.0000x reference)
//
#include <hip/hip_runtime.h>
#include <math.h>

// Problem constants (B, L, H, C) = (2, 512, 128, 25)
#define BB 2
#define LL 512
#define HH 128
#define CC 25
#define W4H 512   // 4*H

// ws layout in floats:
//   T1b [B*L*C]  : t1 + bias
//   T2b [B*L*C]  : t2
//   Wt  [H*64]   : per-h packed rows, [0:25)=W3[:,h], [32:57)=W4[:,h]
#define T1_OFF 0
#define T2_OFF (BB*LL*CC)
#define WT_OFF (2*BB*LL*CC)

#define TL 16
#define TM 16
#define XPITCH 132   // 128 + 4 floats pad -> 528B row stride, conflict-light

__global__ __launch_bounds__(256)
void prep_kernel(const float* __restrict__ x1,
                 const float* __restrict__ x2,
                 const float* __restrict__ W,
                 const float* __restrict__ bias,
                 float* __restrict__ ws) {
    const int tid    = blockIdx.x * blockDim.x + threadIdx.x;
    const int stride = gridDim.x * blockDim.x;
    const int total  = BB * LL * CC;

    // T1b[b,l,c] = sum_h x1[b,l,h] * W1[c,h] + bias[c]
    // T2b[b,m,c] = sum_h x2[b,m,h] * W2[c,h]
    for (int idx = tid; idx < total; idx += stride) {
        const int c  = idx % CC;
        const int bl = idx / CC;
        const float* xr1 = x1 + (size_t)bl * HH;
        const float* xr2 = x2 + (size_t)bl * HH;
        const float* w1  = W + (size_t)c * W4H;        // W[:, 0:H]
        const float* w2  = W + (size_t)c * W4H + HH;   // W[:, H:2H]
        float s1 = 0.f, s2 = 0.f;
        for (int h = 0; h < HH; ++h) {
            s1 = fmaf(xr1[h], w1[h], s1);
            s2 = fmaf(xr2[h], w2[h], s2);
        }
        ws[T1_OFF + idx] = s1 + bias[c];
        ws[T2_OFF + idx] = s2;
    }

    // Wt[h][0:25) = W3[c,h] = W[c*512 + 256 + h]
    // Wt[h][32:57) = W4[c,h] = W[c*512 + 384 + h]
    for (int idx = tid; idx < HH * 64; idx += stride) {
        const int h = idx >> 6;
        const int c = idx & 63;
        float v = 0.f;
        if (c < CC)                    v = W[(size_t)c * W4H + 2*HH + h];
        else if (c >= 32 && c < 32+CC) v = W[(size_t)(c-32) * W4H + 3*HH + h];
        ws[WT_OFF + idx] = v;
    }
}

__global__ __launch_bounds__(256)
void biaffine_main(const float* __restrict__ x1,
                   const float* __restrict__ x2,
                   const float* __restrict__ ws,
                   float* __restrict__ out) {
    __shared__ __align__(16) float x1s[TL * XPITCH];
    __shared__ __align__(16) float x2s[TM * XPITCH];

    const int b  = blockIdx.z;
    const int l0 = blockIdx.y * TL;
    const int m0 = blockIdx.x * TM;
    const int tid = threadIdx.x;

    // Stage x1/x2 tiles (16 rows x 128 floats each) via float4
    {
        const float* src1 = x1 + ((size_t)b * LL + l0) * HH;
        const float* src2 = x2 + ((size_t)b * LL + m0) * HH;
        const int r  = tid >> 5;    // 0..7
        const int c4 = tid & 31;    // float4 index within row
        #pragma unroll
        for (int pass = 0; pass < 2; ++pass) {
            const int row = r + pass * 8;
            float4 v1 = *(const float4*)(src1 + row * HH + c4 * 4);
            float4 v2 = *(const float4*)(src2 + row * HH + c4 * 4);
            *(float4*)(&x1s[row * XPITCH + c4 * 4]) = v1;
            *(float4*)(&x2s[row * XPITCH + c4 * 4]) = v2;
        }
    }
    __syncthreads();

    const int tx = tid & 15;   // m within tile
    const int ty = tid >> 4;   // l within tile

    float acc[CC];
    #pragma unroll
    for (int c = 0; c < CC; ++c) acc[c] = 0.f;

    const float* wt = ws + WT_OFF;
    const float* p1 = &x1s[ty * XPITCH];
    const float* p2 = &x2s[tx * XPITCH];

    for (int h0 = 0; h0 < HH; h0 += 4) {
        const float4 a = *(const float4*)(p1 + h0);
        const float4 q = *(const float4*)(p2 + h0);
        #pragma unroll
        for (int hh = 0; hh < 4; ++hh) {
            const float x1h = ((const float*)&a)[hh];
            const float x2h = ((const float*)&q)[hh];
            const float p = x1h * x2h;
            const float d = fabsf(x1h - x2h);
            const float* wrow = wt + (h0 + hh) * 64;  // wave-uniform -> s_load
            #pragma unroll
            for (int c = 0; c < CC; ++c) {
                acc[c] = fmaf(p, wrow[c],      acc[c]);
                acc[c] = fmaf(d, wrow[32 + c], acc[c]);
            }
        }
    }

    // Epilogue: add t1(+bias) and t2 rows, store 25 floats
    const int l = l0 + ty;
    const int m = m0 + tx;
    const float* t1 = ws + T1_OFF + ((size_t)b * LL + l) * CC;
    const float* t2 = ws + T2_OFF + ((size_t)b * LL + m) * CC;
    float* o = out + (((size_t)b * LL + l) * LL + m) * CC;

    #pragma unroll
    for (int c = 0; c < CC; ++c) {
        o[c] = acc[c] + t1[c] + t2[c];
    }
}

extern "C" void kernel_launch(void* const* d_in, const int* in_sizes, int n_in,
                              void* d_out, int out_size, void* d_ws, size_t ws_size,
                              hipStream_t stream) {
    const float* x1   = (const float*)d_in[0];
    const float* x2   = (const float*)d_in[1];
    const float* W    = (const float*)d_in[2];
    const float* bias = (const float*)d_in[3];
    float* out = (float*)d_out;
    float* ws  = (float*)d_ws;

    prep_kernel<<<128, 256, 0, stream>>>(x1, x2, W, bias, ws);

    dim3 grid(LL / TM, LL / TL, BB);   // (32, 32, 2)
    biaffine_main<<<grid, 256, 0, stream>>>(x1, x2, ws, out);
}

// Round 2
// 107.758 us; speedup vs baseline: 1.5298x; 1.5298x over previous
//
#include <hip/hip_runtime.h>
#include <hip/hip_bf16.h>
#include <math.h>

// (B, L, H, C) = (2, 512, 128, 25)
#define BB 2
#define LL 512
#define HH 128
#define CC 25
#define W4H (4*HH)

typedef __attribute__((ext_vector_type(8))) short short8;
typedef __attribute__((ext_vector_type(4))) float f32x4;

// ws layout:
//   T1b f32 [B*L*C]   @ float offset 0        : t1 + bias
//   T2b f32 [B*L*C]   @ float offset 25600    : t2
//   WfT bf16 [32][256] @ byte offset 204800   : WfT[c][k] = (k<128 ? W3[c][k] : W4[c][k-128]), 0 for c>=25
#define T1_OFF 0
#define T2_OFF (BB*LL*CC)
#define WFT_BYTE_OFF (2*BB*LL*CC*4)

#define MTILE 64   // m rows per block (4 waves x 16)
#define LPB   8    // l rows per block
#define XP    132  // x2 LDS pitch in floats (528 B) -> 2-way max bank aliasing (free)

static __device__ __forceinline__ short f2bf(float f) {
    return __builtin_bit_cast(short, __float2bfloat16(f));
}

__global__ __launch_bounds__(256)
void prep_kernel(const float* __restrict__ x1, const float* __restrict__ x2,
                 const float* __restrict__ W, const float* __restrict__ bias,
                 float* __restrict__ ws)
{
    const int tid    = blockIdx.x * blockDim.x + threadIdx.x;
    const int stride = gridDim.x * blockDim.x;
    const int total  = BB * LL * CC;

    // T1b[b,l,c] = <x1[b,l,:], W1[c,:]> + bias[c] ; T2b[b,m,c] = <x2[b,m,:], W2[c,:]>
    for (int idx = tid; idx < total; idx += stride) {
        const int c  = idx % CC;
        const int bl = idx / CC;
        const float* xr1 = x1 + (size_t)bl * HH;
        const float* xr2 = x2 + (size_t)bl * HH;
        const float* w1  = W + (size_t)c * W4H;
        const float* w2  = w1 + HH;
        float s1 = 0.f, s2 = 0.f;
        #pragma unroll 4
        for (int h = 0; h < HH; ++h) {
            s1 = fmaf(xr1[h], w1[h], s1);
            s2 = fmaf(xr2[h], w2[h], s2);
        }
        ws[T1_OFF + idx] = s1 + bias[c];
        ws[T2_OFF + idx] = s2;
    }

    // Pack W3|W4 transposed as bf16: WfT[c][k], c in [0,32) zero-padded, k in [0,256)
    unsigned short* wft = (unsigned short*)((char*)ws + WFT_BYTE_OFF);
    for (int idx = tid; idx < 32 * 256; idx += stride) {
        const int c = idx >> 8;
        const int k = idx & 255;
        float v = 0.f;
        if (c < CC) v = (k < HH) ? W[(size_t)c * W4H + 2*HH + k]
                                 : W[(size_t)c * W4H + 3*HH + (k - HH)];
        wft[idx] = (unsigned short)f2bf(v);
    }
}

__global__ __launch_bounds__(256)
void biaffine_mfma(const float* __restrict__ x1, const float* __restrict__ x2,
                   const float* __restrict__ ws, float* __restrict__ out)
{
    __shared__ __align__(16) float x2s[MTILE * XP];
    __shared__ __align__(16) float x1s[LPB * HH];

    const int tid = threadIdx.x;
    const int b   = blockIdx.z;
    const int l0  = blockIdx.y * LPB;
    const int m0  = blockIdx.x * MTILE;

    const int lane = tid & 63;
    const int wv   = tid >> 6;      // wave 0..3
    const int q    = lane >> 4;     // k-group 0..3
    const int cn   = lane & 15;     // A-row (m) for input frags; D-col (c) for output

    // ---- persistent B fragments: Bf[tile][kk], k = kk*32 + q*8 + j, c = cn + 16*tile ----
    const unsigned short* wft = (const unsigned short*)((const char*)ws + WFT_BYTE_OFF);
    short8 Bf[2][8];
    #pragma unroll
    for (int t = 0; t < 2; ++t)
        #pragma unroll
        for (int kk = 0; kk < 8; ++kk)
            Bf[t][kk] = *(const short8*)(wft + ((cn + 16*t) * 256 + kk * 32 + q * 8));

    // ---- stage x2 tile (64x128) and x1 rows (LPB x 128) ----
    {
        const float* sx2 = x2 + ((size_t)b * LL + m0) * HH;
        #pragma unroll
        for (int i = 0; i < 8; ++i) {
            const int idx = i * 256 + tid;     // float4 index, 2048 total
            const int r   = idx >> 5;          // 32 float4 per row
            const int c4  = idx & 31;
            f32x4 v = *(const f32x4*)(sx2 + r * HH + c4 * 4);
            *(f32x4*)(&x2s[r * XP + c4 * 4]) = v;
        }
        const float* sx1 = x1 + ((size_t)b * LL + l0) * HH;
        f32x4 v = *(const f32x4*)(sx1 + tid * 4);   // 256 float4 total
        *(f32x4*)(&x1s[tid * 4]) = v;
    }
    __syncthreads();

    const int mrowA = wv * 16 + cn;             // this lane's A-row (m within block tile)
    const float* px2 = &x2s[mrowA * XP];
    const float* Tb1 = ws + T1_OFF;
    const float* Tb2 = ws + T2_OFF;

    // t2 is l-invariant: hoist the per-output-row loads (D row = q*4 + r)
    float t2a[4], t2b[4];
    #pragma unroll
    for (int r = 0; r < 4; ++r) {
        const int mg = m0 + wv * 16 + q * 4 + r;
        t2a[r] = Tb2[((size_t)b * LL + mg) * CC + cn];
        t2b[r] = (cn + 16 < CC) ? Tb2[((size_t)b * LL + mg) * CC + cn + 16] : 0.f;
    }

    for (int l = 0; l < LPB; ++l) {
        const float* px1 = &x1s[l * HH];
        f32x4 acc0 = {0.f, 0.f, 0.f, 0.f};
        f32x4 acc1 = {0.f, 0.f, 0.f, 0.f};

        #pragma unroll
        for (int hh = 0; hh < 4; ++hh) {
            const int hb = hh * 32 + q * 8;
            const f32x4 a0 = *(const f32x4*)(px1 + hb);
            const f32x4 a1 = *(const f32x4*)(px1 + hb + 4);
            const f32x4 b0 = *(const f32x4*)(px2 + hb);
            const f32x4 b1 = *(const f32x4*)(px2 + hb + 4);
            short8 Ap, Ad;
            #pragma unroll
            for (int j = 0; j < 4; ++j) {
                const float xa = a0[j], xb = b0[j];
                Ap[j] = f2bf(xa * xb);
                Ad[j] = f2bf(fabsf(xa - xb));
            }
            #pragma unroll
            for (int j = 0; j < 4; ++j) {
                const float xa = a1[j], xb = b1[j];
                Ap[4 + j] = f2bf(xa * xb);
                Ad[4 + j] = f2bf(fabsf(xa - xb));
            }
            // products hit k in [hh*32, hh*32+32) ; abs-diffs hit k+128
            acc0 = __builtin_amdgcn_mfma_f32_16x16x32_bf16(Ap, Bf[0][hh],     acc0, 0, 0, 0);
            acc1 = __builtin_amdgcn_mfma_f32_16x16x32_bf16(Ap, Bf[1][hh],     acc1, 0, 0, 0);
            acc0 = __builtin_amdgcn_mfma_f32_16x16x32_bf16(Ad, Bf[0][hh + 4], acc0, 0, 0, 0);
            acc1 = __builtin_amdgcn_mfma_f32_16x16x32_bf16(Ad, Bf[1][hh + 4], acc1, 0, 0, 0);
        }

        // epilogue: D col = cn (+16), D row = q*4 + r
        const int lg = l0 + l;
        const float t1a = Tb1[((size_t)b * LL + lg) * CC + cn];
        const float t1b = (cn + 16 < CC) ? Tb1[((size_t)b * LL + lg) * CC + cn + 16] : 0.f;
        #pragma unroll
        for (int r = 0; r < 4; ++r) {
            const int mg = m0 + wv * 16 + q * 4 + r;
            float* o = out + (((size_t)b * LL + lg) * LL + mg) * CC;
            o[cn] = acc0[r] + t1a + t2a[r];
            if (cn + 16 < CC) o[cn + 16] = acc1[r] + t1b + t2b[r];
        }
    }
}

extern "C" void kernel_launch(void* const* d_in, const int* in_sizes, int n_in,
                              void* d_out, int out_size, void* d_ws, size_t ws_size,
                              hipStream_t stream) {
    const float* x1   = (const float*)d_in[0];
    const float* x2   = (const float*)d_in[1];
    const float* W    = (const float*)d_in[2];
    const float* bias = (const float*)d_in[3];
    float* out = (float*)d_out;
    float* ws  = (float*)d_ws;

    prep_kernel<<<256, 256, 0, stream>>>(x1, x2, W, bias, ws);

    dim3 grid(LL / MTILE, LL / LPB, BB);   // (8, 64, 2) = 1024 blocks
    biaffine_mfma<<<grid, 256, 0, stream>>>(x1, x2, ws, out);
}